// Round 9
// baseline (111.167 us; speedup 1.0000x reference)
//
#include <hip/hip_runtime.h>

// Problem constants (fixed by setup_inputs)
constexpr int B   = 256;
constexpr int IN  = 256;
constexpr int OUT = 512;
constexpr double EPSD = 1e-7;

typedef unsigned long long ull;

// ---------------------------------------------------------------------------
// Single fused kernel. Grid = 256 blocks x 512 threads.
// Pre-barrier: setup slices spread across blocks
//   blk   0..127 : RXD (512 elems each)   rxd = 1/(x+eps)   (f64)
//   blk 128..135 : PART (colsum partials, 32 b-rows each)
//   blk 136..151 : XT 64x64 transpose tiles
// Grid barrier: device-scope atomic arrive + spin (all 256 blocks are
//   co-resident: launch_bounds(512,4) caps VGPR<=128 -> 2 blocks/CU capacity,
//   LDS ~46KB -> 2 blocks/CU; so any placement of 256 blocks is resident).
// Post-barrier: R4 main body, o-pair = (2*blk, 2*blk+1).
// ---------------------------------------------------------------------------
__global__ __launch_bounds__(512, 4) void k_fused(
        const float* __restrict__ x, const float* __restrict__ w,
        const float* __restrict__ t,
        double* __restrict__ rxd, double* __restrict__ part,
        float* __restrict__ xt, unsigned* __restrict__ cnt,
        float* __restrict__ out) {
    const int tid = threadIdx.x;
    const int blk = blockIdx.x;

    __shared__ float  tile[64][65];     // setup transpose staging  16.25 KB
    __shared__ double sred[512];        // setup colsum staging      4 KB
    __shared__ double tc[2][B];         // staged t columns          4 KB
    __shared__ double rp[2][2][IN];     // rel partials              8 KB
    __shared__ double rc[2][IN];        // rel columns               4 KB
    __shared__ ull    keys[2][2][B];    // argmax keys               8 KB
    __shared__ ull    swv[8];           // per-wave warg keys

    // ---- setup slice (branch is block-uniform) ----
    if (blk < 128) {                        // RXD: 512 consecutive elements
        const int idx = blk * 512 + tid;
        rxd[idx] = 1.0 / ((double)x[idx] + EPSD);
    } else if (blk < 136) {                 // colsum partial p over 32 b-rows
        const int p = blk - 128;
        const int i = tid & 255, h = tid >> 8;
        const float* xr = x + (size_t)(p * 32 + h * 16) * IN + i;
        double s0 = 0, s1 = 0;
        #pragma unroll
        for (int k = 0; k < 16; k += 2) {
            s0 += (double)xr[k * IN];
            s1 += (double)xr[(k + 1) * IN];
        }
        sred[tid] = s0 + s1;
        __syncthreads();
        if (h == 0) part[p * IN + i] = sred[i] + sred[256 + i];
    } else if (blk < 152) {                 // XT: one 64x64 tile
        const int tl = blk - 136;
        const int r0 = (tl >> 2) * 64, c0 = (tl & 3) * 64;
        const int c  = tid & 63, r8 = (tid >> 6) * 8;
        #pragma unroll
        for (int k = 0; k < 8; ++k)
            tile[r8 + k][c] = x[(size_t)(r0 + r8 + k) * IN + c0 + c];  // coalesced
        __syncthreads();
        #pragma unroll
        for (int k = 0; k < 8; ++k)
            xt[(size_t)(c0 + r8 + k) * B + r0 + c] = tile[c][r8 + k];  // coalesced
    }

    // ---- grid barrier (single-use; cnt zeroed by memset node each launch) ----
    __syncthreads();
    if (tid == 0) {
        __threadfence();                    // flush my block's setup stores
        __hip_atomic_fetch_add(cnt, 1u, __ATOMIC_ACQ_REL, __HIP_MEMORY_SCOPE_AGENT);
        while (__hip_atomic_load(cnt, __ATOMIC_ACQUIRE, __HIP_MEMORY_SCOPE_AGENT) < 256u)
            __builtin_amdgcn_s_sleep(2);
        __threadfence();                    // invalidate stale lines before consuming
    }
    __syncthreads();

    // ---- main body (R4, verbatim): o-pair = (2*blk, 2*blk+1) ----
    const int half = tid >> 8;          // which o of the pair
    const int j    = tid & 255;
    const int o    = blk * 2 + half;

    // stage t column; w-column argmax (w>=0 so f32 bits order-preserving)
    {
        tc[half][j] = (double)t[j * OUT + o];
        float wv = w[j * OUT + o];
        ull key = ((ull)__float_as_uint(wv) << 8) | (unsigned)(255 - j);
        #pragma unroll
        for (int off = 32; off; off >>= 1) {
            ull v = __shfl_down(key, off);
            key = v > key ? v : key;
        }
        if ((tid & 63) == 0) swv[tid >> 6] = key;
    }
    double ps = 0.0;
    #pragma unroll
    for (int k = 0; k < 8; ++k) ps += part[k * IN + j];
    const double rcolv = 1.0 / ps;
    __syncthreads();

    ull wk = swv[half * 4];
    #pragma unroll
    for (int k = 1; k < 4; ++k) { ull v = swv[half * 4 + k]; wk = v > wk ? v : wk; }
    const int warg_o = 255 - (int)(wk & 0xFFull);

    // phase 1: rel partials; thread = (i-pair, b-half)
    {
        const int i0 = (j & 127) * 2;
        const int bh = j >> 7;
        const double* __restrict__ tcc  = tc[half] + bh * 128;
        const double* __restrict__ base = rxd + (size_t)(bh * 128) * IN + i0;
        double a0 = 0, a1 = 0, a2 = 0, a3 = 0;
        #pragma unroll 8
        for (int k = 0; k < 128; k += 2) {
            double2 r0 = *(const double2*)(base + (size_t)k * IN);
            double2 r1 = *(const double2*)(base + (size_t)(k + 1) * IN);
            double t0 = tcc[k], t1 = tcc[k + 1];
            a0 += fmin(t0 * r0.x, 1.0);
            a1 += fmin(t0 * r0.y, 1.0);
            a2 += fmin(t1 * r1.x, 1.0);
            a3 += fmin(t1 * r1.y, 1.0);
        }
        rp[half][bh][i0]     = a0 + a2;
        rp[half][bh][i0 + 1] = a1 + a3;
    }
    __syncthreads();
    rc[half][j] = (rp[half][0][j] + rp[half][1][j]) * rcolv;   // i = j
    __syncthreads();

    // phase 2: argmax_i x[b,i]*rel[i,o]; thread = (b-pair, i-half)
    {
        const int b0 = (j & 127) * 2;
        const int ih = j >> 7;
        const double* __restrict__ rcc = rc[half];
        double mA0 = -1.0, mA1 = -1.0, mB0 = -1.0, mB1 = -1.0;
        #pragma unroll 8
        for (int i = ih * 128; i < ih * 128 + 128; i += 2) {
            float2 x0 = *(const float2*)&xt[(size_t)i * B + b0];
            float2 x1 = *(const float2*)&xt[(size_t)(i + 1) * B + b0];
            double s00 = (double)x0.x * rcc[i];
            double s01 = (double)x0.y * rcc[i];
            double s10 = (double)x1.x * rcc[i + 1];
            double s11 = (double)x1.y * rcc[i + 1];
            long long u00 = (__double_as_longlong(s00) & ~0xFFll) | (long long)(255 - i);
            long long u01 = (__double_as_longlong(s01) & ~0xFFll) | (long long)(255 - i);
            long long u10 = (__double_as_longlong(s10) & ~0xFFll) | (long long)(255 - (i + 1));
            long long u11 = (__double_as_longlong(s11) & ~0xFFll) | (long long)(255 - (i + 1));
            mA0 = fmax(mA0, __longlong_as_double(u00));
            mB0 = fmax(mB0, __longlong_as_double(u01));
            mA1 = fmax(mA1, __longlong_as_double(u10));
            mB1 = fmax(mB1, __longlong_as_double(u11));
        }
        keys[half][ih][b0]     = (ull)__double_as_longlong(fmax(mA0, mA1));
        keys[half][ih][b0 + 1] = (ull)__double_as_longlong(fmax(mB0, mB1));
    }
    __syncthreads();

    // finish: thread (half, j) handles (o, b=j)
    {
        const int b = j;
        ull k0 = keys[half][0][b], k1 = keys[half][1][b];
        ull mk = k0 > k1 ? k0 : k1;          // positive doubles: bit order = value order
        const int ia = 255 - (int)(mk & 0xFFull);

        float* __restrict__ out0 = out;
        float* __restrict__ out1 = out + (size_t)B * OUT;
        out0[b * OUT + o] = xt[(size_t)ia * B + b] * w[ia * OUT + o];

        const int iw = (tc[half][b] > 0.0) ? warg_o : 0;
        out1[b * OUT + o] = xt[(size_t)iw * B + b] * w[iw * OUT + o];
    }
}

// ---------------------------------------------------------------------------
extern "C" void kernel_launch(void* const* d_in, const int* in_sizes, int n_in,
                              void* d_out, int out_size, void* d_ws, size_t ws_size,
                              hipStream_t stream) {
    const float* x = (const float*)d_in[0];   // (B, IN)
    const float* w = (const float*)d_in[1];   // (IN, OUT)
    const float* t = (const float*)d_in[2];   // (B, OUT)
    float* out = (float*)d_out;               // 2 * B * OUT floats

    double*   dws  = (double*)d_ws;
    double*   RXD  = dws;                            // B*IN doubles (512 KB)
    double*   PART = RXD + (size_t)B * IN;           // 8*IN doubles (16 KB)
    float*    XT   = (float*)(PART + 8 * IN);        // IN*B floats  (256 KB)
    unsigned* CNT  = (unsigned*)(XT + (size_t)IN * B);

    hipMemsetAsync(CNT, 0, sizeof(unsigned), stream);   // reset barrier counter
    k_fused<<<256, 512, 0, stream>>>(x, w, t, RXD, PART, XT, CNT, out);
}

// Round 10
// 82.709 us; speedup vs baseline: 1.3441x; 1.3441x over previous
//
#include <hip/hip_runtime.h>

// Problem constants (fixed by setup_inputs)
constexpr int B   = 256;
constexpr int IN  = 256;
constexpr int OUT = 512;
constexpr double EPSD = 1e-7;

typedef unsigned long long ull;

// ---------------------------------------------------------------------------
// Workspace:
//   RXD  [B][IN]  f64  (512 KB)  1/(x+eps)
//   PART [8][IN]  f64  (16 KB)   partial colsums of x
//   XT   [IN][B]  f32  (256 KB)  x transposed
// ---------------------------------------------------------------------------

__global__ __launch_bounds__(256) void k_setup(const float* __restrict__ x,
        double* __restrict__ rxd, double* __restrict__ part, float* __restrict__ xt) {
    const int tid = threadIdx.x;
    const int blk = blockIdx.x;
    if (blk < 32) {                          // RXD: 8 b-rows per block, coalesced
        const int b0 = blk * 8;
        #pragma unroll
        for (int k = 0; k < 8; ++k)
            rxd[(b0 + k) * IN + tid] = 1.0 / ((double)x[(b0 + k) * IN + tid] + EPSD);
    } else if (blk < 40) {                   // partial colsums: 32 b-rows per block
        const int j = blk - 32, b0 = j * 32;
        double s0 = 0, s1 = 0, s2 = 0, s3 = 0;
        #pragma unroll
        for (int k = 0; k < 32; k += 4) {
            s0 += (double)x[(b0 + k + 0) * IN + tid];
            s1 += (double)x[(b0 + k + 1) * IN + tid];
            s2 += (double)x[(b0 + k + 2) * IN + tid];
            s3 += (double)x[(b0 + k + 3) * IN + tid];
        }
        part[j * IN + tid] = (s0 + s1) + (s2 + s3);
    } else {                                 // XT: LDS-tiled 64x64 transpose, 16 tiles
        __shared__ float tile[64][65];
        const int tl  = blk - 40;            // 0..15
        const int tr0 = (tl >> 2) * 64;      // b-tile origin (rows of x)
        const int tc0 = (tl & 3) * 64;       // i-tile origin (cols of x)
        const int c   = tid & 63;
        const int r4  = tid >> 6;            // 0..3
        #pragma unroll
        for (int k = 0; k < 16; ++k) {
            const int r = r4 + k * 4;
            tile[r][c] = x[(tr0 + r) * IN + tc0 + c];     // coalesced read
        }
        __syncthreads();
        #pragma unroll
        for (int k = 0; k < 16; ++k) {
            const int r = r4 + k * 4;                      // i-local
            xt[(size_t)(tc0 + r) * B + tr0 + c] = tile[c][r];  // coalesced write
        }
    }
}

// ---------------------------------------------------------------------------
// Merged main kernel: one block per o, 512 threads, 2 blocks/CU.
//   Phase W: argmax_i w[i,o] (first-max) via 64-bit-key shfl reduce (waves 0-3).
//   Phase 1: rel partials; thread = (i-pair, b-quarter); double2 rxd loads.
//   Phase 2: out0 argmax; thread = (b-pair, i-quarter); float2 xt loads;
//            index-embedded f64 max keys; 4-way LDS combine.
// ---------------------------------------------------------------------------
__global__ __launch_bounds__(512, 4) void k_main(const float* __restrict__ w,
        const float* __restrict__ t, const double* __restrict__ rxd,
        const double* __restrict__ part, const float* __restrict__ xt,
        float* __restrict__ out) {
    const int tid = threadIdx.x;
    const int j   = tid & 255;
    const int o   = blockIdx.x;

    __shared__ double tc[B];          // staged t column (f64)      2 KB
    __shared__ double rcs[IN];        // 1/colsum per i             2 KB
    __shared__ double rp[4][IN];      // rel partials [bq][i]       8 KB
    __shared__ double rc[IN];         // rel column                 2 KB
    __shared__ ull    keys[4][B];     // argmax keys [iq][b]        8 KB
    __shared__ ull    swv[4];         // per-wave warg keys

    int warg_o = 0;
    if (tid < 256) {
        // stage t column + per-i reciprocal colsum
        tc[j] = (double)t[j * OUT + o];
        double ps = 0.0;
        #pragma unroll
        for (int k = 0; k < 8; ++k) ps += part[k * IN + j];
        rcs[j] = 1.0 / ps;
        // w-column argmax (w>=0 so f32 bits are order-preserving)
        float wv = w[j * OUT + o];
        ull key = ((ull)__float_as_uint(wv) << 8) | (unsigned)(255 - j);
        #pragma unroll
        for (int off = 32; off; off >>= 1) {
            ull v = __shfl_down(key, off);
            key = v > key ? v : key;
        }
        if ((tid & 63) == 0) swv[tid >> 6] = key;
    }
    __syncthreads();
    if (tid < 256) {
        ull wk = swv[0];
        #pragma unroll
        for (int k = 1; k < 4; ++k) { ull v = swv[k]; wk = v > wk ? v : wk; }
        warg_o = 255 - (int)(wk & 0xFFull);
    }

    // --- phase 1: rel partials; thread = (i-pair, b-quarter of 64) ---
    {
        const int i0 = (tid & 127) * 2;
        const int bq = tid >> 7;                    // 0..3
        const double* __restrict__ tcc  = tc + bq * 64;
        const double* __restrict__ base = rxd + (size_t)(bq * 64) * IN + i0;
        double a0 = 0, a1 = 0, a2 = 0, a3 = 0;
        #pragma unroll 8
        for (int k = 0; k < 64; k += 2) {
            double2 r0 = *(const double2*)(base + (size_t)k * IN);
            double2 r1 = *(const double2*)(base + (size_t)(k + 1) * IN);
            double t0 = tcc[k], t1 = tcc[k + 1];
            a0 += fmin(t0 * r0.x, 1.0);
            a1 += fmin(t0 * r0.y, 1.0);
            a2 += fmin(t1 * r1.x, 1.0);
            a3 += fmin(t1 * r1.y, 1.0);
        }
        rp[bq][i0]     = a0 + a2;
        rp[bq][i0 + 1] = a1 + a3;
    }
    __syncthreads();
    if (tid < 256)
        rc[j] = (((rp[0][j] + rp[1][j]) + (rp[2][j] + rp[3][j]))) * rcs[j];
    __syncthreads();

    // --- phase 2: argmax_i x[b,i]*rel[i,o]; thread = (b-pair, i-quarter) ---
    {
        const int b0 = (tid & 127) * 2;
        const int iq = tid >> 7;                    // 0..3
        double mA0 = -1.0, mA1 = -1.0, mB0 = -1.0, mB1 = -1.0;
        #pragma unroll 8
        for (int i = iq * 64; i < iq * 64 + 64; i += 2) {
            float2 x0 = *(const float2*)&xt[(size_t)i * B + b0];
            float2 x1 = *(const float2*)&xt[(size_t)(i + 1) * B + b0];
            double s00 = (double)x0.x * rc[i];
            double s01 = (double)x0.y * rc[i];
            double s10 = (double)x1.x * rc[i + 1];
            double s11 = (double)x1.y * rc[i + 1];
            long long u00 = (__double_as_longlong(s00) & ~0xFFll) | (long long)(255 - i);
            long long u01 = (__double_as_longlong(s01) & ~0xFFll) | (long long)(255 - i);
            long long u10 = (__double_as_longlong(s10) & ~0xFFll) | (long long)(255 - (i + 1));
            long long u11 = (__double_as_longlong(s11) & ~0xFFll) | (long long)(255 - (i + 1));
            mA0 = fmax(mA0, __longlong_as_double(u00));
            mB0 = fmax(mB0, __longlong_as_double(u01));
            mA1 = fmax(mA1, __longlong_as_double(u10));
            mB1 = fmax(mB1, __longlong_as_double(u11));
        }
        keys[iq][b0]     = (ull)__double_as_longlong(fmax(mA0, mA1));
        keys[iq][b0 + 1] = (ull)__double_as_longlong(fmax(mB0, mB1));
    }
    __syncthreads();

    // --- finish: thread j handles b = j ---
    if (tid < 256) {
        const int b = j;
        ull mk = keys[0][b];
        #pragma unroll
        for (int k = 1; k < 4; ++k) { ull v = keys[k][b]; mk = v > mk ? v : mk; }
        const int ia = 255 - (int)(mk & 0xFFull);

        float* __restrict__ out0 = out;
        float* __restrict__ out1 = out + (size_t)B * OUT;
        out0[b * OUT + o] = xt[(size_t)ia * B + b] * w[ia * OUT + o];

        const int iw = (tc[b] > 0.0) ? warg_o : 0;
        out1[b * OUT + o] = xt[(size_t)iw * B + b] * w[iw * OUT + o];
    }
}

// ---------------------------------------------------------------------------
extern "C" void kernel_launch(void* const* d_in, const int* in_sizes, int n_in,
                              void* d_out, int out_size, void* d_ws, size_t ws_size,
                              hipStream_t stream) {
    const float* x = (const float*)d_in[0];   // (B, IN)
    const float* w = (const float*)d_in[1];   // (IN, OUT)
    const float* t = (const float*)d_in[2];   // (B, OUT)
    float* out = (float*)d_out;               // 2 * B * OUT floats

    double* dws  = (double*)d_ws;
    double* RXD  = dws;                             // B*IN doubles (512 KB)
    double* PART = RXD + (size_t)B * IN;            // 8*IN doubles (16 KB)
    float*  XT   = (float*)(PART + 8 * IN);         // IN*B floats  (256 KB)

    k_setup<<<56, 256, 0, stream>>>(x, RXD, PART, XT);
    k_main<<<OUT, 512, 0, stream>>>(w, t, RXD, PART, XT, out);
}